// Round 2
// baseline (93.193 us; speedup 1.0000x reference)
//
#include <hip/hip_runtime.h>

// PrRoIPool2D forward, MI355X. B=8, C=256, H=W=48, R=300, 7x7 bins, scale=1/16.
// R12: fused kernel + XOR-swizzled LDS (bank-conflict fix).
//  - patch layout: 128B line per (j,i4) cell; 16B slot = ((il<<1)|q) ^ ((j+i4)&7)
//    -> P1 ds_write_b128 and PA ds_read_b128 spread over all 32 banks
//    (old layout: spatial stride 32B == 0 mod 32 banks -> up to ~32-way conflicts)
//  - rs layout: 16B half = q ^ (j&1) -> PB ds_read_b64 spread 2x
//  - PA wx weights computed per-thread into REGISTERS before the barrier
//    (overlaps P1 HBM latency; removes pbuf from PA critical path) [R10 trick]
//  - bounds recomputed redundantly per thread; wy/bj/inv_area by lanes 0..7
// Phases: P1 stage patch -> PA row-sums rs[pw][j][c8] -> PB combine.
// LDS 26.2 KB -> 6 blocks/CU. Numerics identical to R10/R11 (placement-only).

#define PH 7
#define PW 7
#define NBINS 49
#define SCALE 0.0625f
#define CH 256
#define FH 48
#define FW 48
#define RNUM 300
#define CB 8                 // channels per block
#define MAXJ 23              // max patch rows
#define NL 7                 // 16-float-wide cells per row (ROWF/4)
// pbuf: [0+ph*6]: wy[7][6] | [84+ph]: bj (int, rel J0) | [98]: inv_area

__device__ __forceinline__ float hat_int(float x, float g) {
    float t = x - (g - 1.0f);
    if (t <= 0.0f) return 0.0f;
    if (t <= 1.0f) return 0.5f * t * t;
    if (t <= 2.0f) { float u = 2.0f - t; return 1.0f - 0.5f * u * u; }
    return 1.0f;
}

__global__ __launch_bounds__(256)
void prroi_fused(const float* __restrict__ feat,
                 const float* __restrict__ rois,
                 float* __restrict__ out) {
    const int cblk = blockIdx.x;        // 0..31
    const int r    = blockIdx.y;        // 0..299
    const int c0   = cblk * CB;
    const int tid  = threadIdx.x;

    // patch: [j][i4] cells of 32 floats (128 B line), slots XOR-swizzled
    __shared__ float patch[MAXJ * NL * 32];     // 20608 B
    __shared__ float rs[PW * MAXJ * CB];        // [pw][j][c8]  5152 B
    __shared__ float pbuf[99];                  // wy/bj/inv_area  396 B

    // ---- redundant per-thread ROI bounds ----
    const float* roi = rois + r * 5;
    const int   b  = (int)roi[0];
    const float x1 = roi[1] * SCALE, y1 = roi[2] * SCALE;
    const float x2 = roi[3] * SCALE, y2 = roi[4] * SCALE;
    const float ylo = fminf(y1, y2), yhi = fmaxf(y1, y2);
    const float xlo = fminf(x1, x2), xhi = fmaxf(x1, x2);
    const int j1 = min(FH - 1, (int)floorf(yhi) + 1);
    const int i1 = min(FW - 1, (int)floorf(xhi) + 1);
    const int J0 = min(max(0, (int)floorf(ylo) - 1), FH - 6);
    const int I0 = min(max(0, (int)floorf(xlo) - 1) & ~3, FW - 8);
    const int JROWS = min(FH - J0, max(j1 - J0 + 1, 6));        // 6..23
    int NI4 = min(((i1 - I0) >> 2) + 1, (FW - I0) >> 2);
    NI4 = max(NI4, 2);                                           // 2..7

    // ---- PA unit decode + per-thread register weights (pre-barrier) ----
    const float roi_w = fmaxf(x2 - x1, 0.0f);
    const float bin_w = roi_w / (float)PW;
    const int nA = JROWS * 14;
    int pw1 = 0, q1 = 0, j1r = 0, pw2 = 0, q2 = 0, j2r = 0, bi1 = 0, bi2 = 0;
    float wxa[6], wxb[6];
    const bool a1 = tid < nA, a2 = (tid + 256) < nA;
    if (a1) {
        j1r = tid / 14; const int rem = tid - j1r * 14; pw1 = rem >> 1; q1 = rem & 1;
        const float xa = x1 + pw1 * bin_w, xb = xa + bin_w;
        const int base = min(max((int)floorf(xa) - 1, I0), I0 + 4 * NI4 - 6);
        bi1 = base - I0;
#pragma unroll
        for (int k = 0; k < 6; ++k) {
            const float g = (float)(base + k);
            wxa[k] = hat_int(xb, g) - hat_int(xa, g);
        }
    }
    if (a2) {
        const int v2 = tid + 256;
        j2r = v2 / 14; const int rem = v2 - j2r * 14; pw2 = rem >> 1; q2 = rem & 1;
        const float xa = x1 + pw2 * bin_w, xb = xa + bin_w;
        const int base = min(max((int)floorf(xa) - 1, I0), I0 + 4 * NI4 - 6);
        bi2 = base - I0;
#pragma unroll
        for (int k = 0; k < 6; ++k) {
            const float g = (float)(base + k);
            wxb[k] = hat_int(xb, g) - hat_int(xa, g);
        }
    }

    // ---- P1: stage patch rectangle, channel-fast, swizzled LDS writes ----
    const float* fb = feat + (size_t)(b * CH + c0) * FH * FW;
    const int J7 = JROWS * NL;
    for (int u = tid; u < 2 * J7; u += 256) {    // <= 322, 1 pass typical
        const int q  = (u >= J7) ? 1 : 0;
        const int rm = u - q * J7;
        const int j  = rm / NL;
        const int i4 = rm - j * NL;
        if (i4 < NI4) {
            const int ig = I0 + 4 * i4;           // <= FW-4 by construction
            const float* src = fb + ((size_t)(4 * q) * FH + (J0 + j)) * FW + ig;
            const float4 v0  = *(const float4*)(src);
            const float4 v1v = *(const float4*)(src + FH * FW);
            const float4 v2v = *(const float4*)(src + 2 * FH * FW);
            const float4 v3v = *(const float4*)(src + 3 * FH * FW);
            const int msk = (j + i4) & 7;
            float* dl = &patch[(j * NL + i4) * 32];
            *(float4*)(dl + (((0 | q) ^ msk) << 2)) = make_float4(v0.x, v1v.x, v2v.x, v3v.x);
            *(float4*)(dl + (((2 | q) ^ msk) << 2)) = make_float4(v0.y, v1v.y, v2v.y, v3v.y);
            *(float4*)(dl + (((4 | q) ^ msk) << 2)) = make_float4(v0.z, v1v.z, v2v.z, v3v.z);
            *(float4*)(dl + (((6 | q) ^ msk) << 2)) = make_float4(v0.w, v1v.w, v2v.w, v3v.w);
        }
    }

    // ---- wy/bj/inv_area by lanes 0..7 (overlaps P1 latency) ----
    const float roi_h = fmaxf(y2 - y1, 0.0f);
    const float bin_h = roi_h / (float)PH;
    if (tid < PH) {
        const int ph = tid;
        const float ya = y1 + ph * bin_h, yb = ya + bin_h;
        const int base = min(max((int)floorf(ya) - 1, J0), J0 + JROWS - 6);
        pbuf[84 + ph] = __int_as_float(base - J0);
#pragma unroll
        for (int k = 0; k < 6; ++k) {
            const float g = (float)(base + k);
            pbuf[ph * 6 + k] = hat_int(yb, g) - hat_int(ya, g);
        }
    } else if (tid == PH) {
        const float area = bin_w * bin_h;
        pbuf[98] = (area > 0.0f) ? (1.0f / area) : 0.0f;
    }
    __syncthreads();

    // ---- PA: rs[pw][j][c8] = sum_i wx * patch (weights in regs) ----
    if (a1) {
        float ax = 0.0f, ay = 0.0f, az = 0.0f, aw = 0.0f;
#pragma unroll
        for (int ii = 0; ii < 6; ++ii) {
            const float w = wxa[ii];
            const int i  = bi1 + ii;
            const int i4 = i >> 2, il = i & 3;
            const int slot = ((il << 1) | q1) ^ ((j1r + i4) & 7);
            const float4 v = *(const float4*)(&patch[(j1r * NL + i4) * 32 + (slot << 2)]);
            ax += w * v.x; ay += w * v.y; az += w * v.z; aw += w * v.w;
        }
        *(float4*)(&rs[((size_t)pw1 * MAXJ + j1r) * CB + ((q1 ^ (j1r & 1)) << 2)]) =
            make_float4(ax, ay, az, aw);
    }
    if (a2) {
        float ax = 0.0f, ay = 0.0f, az = 0.0f, aw = 0.0f;
#pragma unroll
        for (int ii = 0; ii < 6; ++ii) {
            const float w = wxb[ii];
            const int i  = bi2 + ii;
            const int i4 = i >> 2, il = i & 3;
            const int slot = ((il << 1) | q2) ^ ((j2r + i4) & 7);
            const float4 v = *(const float4*)(&patch[(j2r * NL + i4) * 32 + (slot << 2)]);
            ax += w * v.x; ay += w * v.y; az += w * v.z; aw += w * v.w;
        }
        *(float4*)(&rs[((size_t)pw2 * MAXJ + j2r) * CB + ((q2 ^ (j2r & 1)) << 2)]) =
            make_float4(ax, ay, az, aw);
    }
    __syncthreads();

    // ---- PB: combine over rows, float2 channel-pairs, swizzled rs reads ----
    const int bin = tid & 63;
    const int cp  = tid >> 6;
    if (bin < NBINS) {
        const int phv = bin / PW, pwv = bin - phv * PW;
        const int bj = __float_as_int(pbuf[84 + phv]);
        const float inv_area = pbuf[98];
        const int qh = cp >> 1, lo = (cp & 1) * 2;
        float ax = 0.0f, ay = 0.0f;
#pragma unroll
        for (int jj = 0; jj < 6; ++jj) {
            const int j = bj + jj;
            const float w = pbuf[phv * 6 + jj];
            const float2 v = *(const float2*)(
                &rs[((size_t)pwv * MAXJ + j) * CB + ((qh ^ (j & 1)) << 2) + lo]);
            ax += w * v.x; ay += w * v.y;
        }
        float* o = out + ((size_t)r * CH + c0 + 2 * cp) * NBINS + bin;
        o[0]     = ax * inv_area;
        o[NBINS] = ay * inv_area;
    }
}

extern "C" void kernel_launch(void* const* d_in, const int* in_sizes, int n_in,
                              void* d_out, int out_size, void* d_ws, size_t ws_size,
                              hipStream_t stream) {
    const float* feat = (const float*)d_in[0];
    const float* rois = (const float*)d_in[1];
    float* out = (float*)d_out;
    (void)d_ws; (void)ws_size;

    prroi_fused<<<dim3(CH / CB, RNUM), 256, 0, stream>>>(feat, rois, out);
}